// Round 1
// baseline (251.493 us; speedup 1.0000x reference)
//
#include <hip/hip_runtime.h>
#include <stdint.h>

// AlbertSeq2Seq fused pipeline, bf16 MFMA implementation.
// Shapes: B=4, T=S=1024, H=1024, heads=16, d=64.
// Workspace layout (needs ws_size >= 72 MB):
//   [0,8)MB   dec_bf   (later reused as ctx)
//   [8,16)MB  enc_bf   (later reused as proj)
//   [16,24)MB Wq_bf,Wk_bf,Wv_bf,Wd_bf (2MB each)
//   [24,32)MB q1
//   [32,40)MB k1       (later reused as self_out)
//   [40,48)MB v1       (later reused as evt)
//   [48,56)MB ek
//   [56,64)MB ev
//   [64,72)MB vt1

#define B_   4
#define T_   1024
#define S_   1024
#define H_   1024
#define LOG2E 1.44269504088896340736f

typedef __attribute__((ext_vector_type(8)))  __bf16       bf16x8;
typedef __attribute__((ext_vector_type(4)))  float        f32x4;
typedef __attribute__((ext_vector_type(4)))  unsigned int uint4v;

static __device__ __forceinline__ float bf2f(unsigned int u) {
    return __builtin_bit_cast(float, u << 16);
}
static __device__ __forceinline__ unsigned short f2bf(float f) {
    unsigned int x = __builtin_bit_cast(unsigned int, f);
    return (unsigned short)((x + 0x7fffu + ((x >> 16) & 1u)) >> 16);
}
static __device__ __forceinline__ f32x4 mfma16(bf16x8 a, bf16x8 b, f32x4 c) {
    return __builtin_amdgcn_mfma_f32_16x16x32_bf16(a, b, c, 0, 0, 0);
}

typedef const __attribute__((address_space(1))) void gv_t;
typedef __attribute__((address_space(3))) void lv_t;
// async global->LDS, 16B per lane; l must be wave-uniform base (lane*16 is implicit)
static __device__ __forceinline__ void g2lds16(const void* g, void* l) {
    __builtin_amdgcn_global_load_lds((gv_t*)(size_t)g, (lv_t*)(unsigned int)(size_t)l, 16, 0, 0);
}

// ---------------- fp32 -> bf16 convert ----------------
__global__ __launch_bounds__(256)
void cvt_bf16(const float* __restrict__ in, unsigned short* __restrict__ out, int n4) {
    int i = blockIdx.x * 256 + threadIdx.x;
    if (i >= n4) return;
    float4 v = ((const float4*)in)[i];
    uint2 o;
    o.x = (unsigned)f2bf(v.x) | ((unsigned)f2bf(v.y) << 16);
    o.y = (unsigned)f2bf(v.z) | ((unsigned)f2bf(v.w) << 16);
    ((uint2*)out)[i] = o;
}

// ---------------- GEMM: C = A @ W^T + bias, all [*,1024] row-major bf16 ----------------
// 128x128 tile, BK=32, 4 waves (2x2), each wave 64x64 = 4x4 frags of 16x16x32.
// blockIdx.y selects weight/out set: ysel = y>>3 (8 n-tiles per 1024-wide output).
__global__ __launch_bounds__(256, 2)
void gemm_bf16(const unsigned short* __restrict__ A,
               const unsigned short* __restrict__ W0,
               const unsigned short* __restrict__ W1,
               const unsigned short* __restrict__ W2,
               const float* __restrict__ bias0,
               const float* __restrict__ bias1,
               const float* __restrict__ bias2,
               unsigned short* __restrict__ O0,
               unsigned short* __restrict__ O1,
               unsigned short* __restrict__ O2)
{
    __shared__ char smem[16384];
    char* As = smem;
    char* Bs = smem + 8192;
    const int tid = threadIdx.x;
    const int lane = tid & 63;
    const int w = tid >> 6;
    const int c = lane & 15, g = lane >> 4;
    const int wm = (w >> 1) * 64, wn = (w & 1) * 64;
    const int m0 = blockIdx.x * 128;
    const int ysel = blockIdx.y >> 3;
    const int n0 = (blockIdx.y & 7) * 128;
    const unsigned short* W = (ysel == 0) ? W0 : ((ysel == 1) ? W1 : W2);
    const float* bias        = (ysel == 0) ? bias0 : ((ysel == 1) ? bias1 : bias2);
    unsigned short* O        = (ysel == 0) ? O0 : ((ysel == 1) ? O1 : O2);

    f32x4 acc[4][4];
#pragma unroll
    for (int i = 0; i < 4; i++)
#pragma unroll
        for (int j = 0; j < 4; j++) acc[i][j] = (f32x4){0.f, 0.f, 0.f, 0.f};

    // staging: per wave 16 rows x 64B; lane -> (row = w*16 + lane/4, 16B seg = lane&3)
    const int srow = w * 16 + (lane >> 2);
    const int scol = (lane & 3) * 8;
    const unsigned short* gA = A + (size_t)(m0 + srow) * 1024 + scol;
    const unsigned short* gB = W + (size_t)(n0 + srow) * 1024 + scol;
    char* lA = As + w * 1024;   // wave-uniform LDS base
    char* lB = Bs + w * 1024;

    for (int kk = 0; kk < 1024; kk += 32) {
        g2lds16(gA + kk,           lA);
        g2lds16(gA + kk + 64*1024, lA + 4096);
        g2lds16(gB + kk,           lB);
        g2lds16(gB + kk + 64*1024, lB + 4096);
        __syncthreads();
        bf16x8 af[4], bfr[4];
#pragma unroll
        for (int t = 0; t < 4; t++) {
            af[t]  = *(const bf16x8*)(As + (wm + t*16 + c)*64 + g*16);
            bfr[t] = *(const bf16x8*)(Bs + (wn + t*16 + c)*64 + g*16);
        }
#pragma unroll
        for (int i = 0; i < 4; i++)
#pragma unroll
            for (int j = 0; j < 4; j++)
                acc[i][j] = mfma16(af[i], bfr[j], acc[i][j]);
        __syncthreads();
    }

    float bv[4];
#pragma unroll
    for (int j = 0; j < 4; j++) bv[j] = bias[n0 + wn + j*16 + c];
#pragma unroll
    for (int i = 0; i < 4; i++) {
        const int mrow = m0 + wm + i*16 + g*4;
#pragma unroll
        for (int r = 0; r < 4; r++) {
            unsigned short* orow = O + (size_t)(mrow + r) * 1024 + n0 + wn + c;
#pragma unroll
            for (int j = 0; j < 4; j++)
                orow[j*16] = f2bf(acc[i][j][r] + bv[j]);
        }
    }
}

// ---------------- per-head V transpose: V[b,s,h*64+d] -> VT[(b*16+h)*64+d][s] ----------------
__global__ __launch_bounds__(256)
void transpose_v(const unsigned short* __restrict__ V, unsigned short* __restrict__ VT)
{
    __shared__ char sm[8192];
    const int tid = threadIdx.x;
    const int bh = blockIdx.y, b = bh >> 4, h = bh & 15;
    const int s0 = blockIdx.x * 64;
    for (int u = tid; u < 512; u += 256) {
        const int r = u >> 3, sg = u & 7;
        uint4 v = *(const uint4*)(V + (size_t)(b*S_ + s0 + r)*H_ + h*64 + sg*8);
        *(uint4*)(sm + r*128 + ((sg*16) ^ ((r & 7) << 4))) = v;
    }
    __syncthreads();
    const int d = tid >> 2, ss = tid & 3;
    unsigned int ow[8];
#pragma unroll
    for (int j2 = 0; j2 < 8; j2++) {
        const int s_a = ss*16 + 2*j2, s_b = s_a + 1;
        unsigned int ta = *(const unsigned short*)(sm + s_a*128 + ((2*d) ^ ((s_a & 7) << 4)));
        unsigned int tb = *(const unsigned short*)(sm + s_b*128 + ((2*d) ^ ((s_b & 7) << 4)));
        ow[j2] = ta | (tb << 16);
    }
    unsigned short* op = VT + (size_t)(bh*64 + d)*S_ + s0 + ss*16;
    uint4 o0, o1;
    o0.x = ow[0]; o0.y = ow[1]; o0.z = ow[2]; o0.w = ow[3];
    o1.x = ow[4]; o1.y = ow[5]; o1.z = ow[6]; o1.w = ow[7];
    *(uint4*)op = o0;
    *(uint4*)(op + 8) = o1;
}

// ---------------- fused flash attention ----------------
// grid (T/64, B*NH), 256 threads (4 waves). Wave w owns 16 q-rows (q = q0+w*16+c).
// Swapped QK^T: S^T = mfma(A=K, B=Q)  -> s lives on MFMA-M, q on lanes (col=c).
// PV:           O^T = mfma(A=V^T, B=P^T); P^T B-frags built in-register via shfl.
__global__ __launch_bounds__(256, 2)
void attn_fused(const unsigned short* __restrict__ Q,
                const unsigned short* __restrict__ Kx,
                const unsigned short* __restrict__ VT,
                const float* __restrict__ mask,
                unsigned short* __restrict__ Octx)
{
    __shared__ char smem[16640];
    char* Ks = smem;            // 8KB [64 s][64 d], XOR-swizzled rows
    char* Vs = smem + 8192;     // 8KB [64 d][64 s], XOR-swizzled rows
    float* mLds = (float*)(smem + 16384);
    const int tid = threadIdx.x;
    const int lane = tid & 63, w = tid >> 6;
    const int c = lane & 15, g = lane >> 4;
    const int bh = blockIdx.y, b = bh >> 4, h = bh & 15;
    const int q0 = blockIdx.x * 64;
    const int qrow = q0 + w*16 + c;

    const unsigned short* qptr = Q + (size_t)(b*T_ + qrow)*H_ + h*64;
    const bf16x8 bq0 = *(const bf16x8*)(qptr + g*8);        // d = 0..31 chunk
    const bf16x8 bq1 = *(const bf16x8*)(qptr + 32 + g*8);   // d = 32..63 chunk

    f32x4 o[4];
#pragma unroll
    for (int mf = 0; mf < 4; mf++) o[mf] = (f32x4){0.f, 0.f, 0.f, 0.f};
    float m_run = -3.0e38f, l_run = 0.f;

    const unsigned short* kbase0 = Kx + (size_t)b*S_*H_ + h*64;
    const unsigned short* vbase0 = VT + (size_t)(bh*64)*S_;

    for (int it = 0; it < S_/64; ++it) {
        const int s0 = it * 64;
        for (int u = tid; u < 512; u += 256) {
            const int r = u >> 3, sg = u & 7;
            uint4 kv = *(const uint4*)(kbase0 + (size_t)(s0 + r)*H_ + sg*8);
            *(uint4*)(Ks + r*128 + ((sg*16) ^ ((r & 7) << 4))) = kv;
            uint4 vv = *(const uint4*)(vbase0 + (size_t)r*S_ + s0 + sg*8);
            *(uint4*)(Vs + r*128 + ((sg*16) ^ ((r & 7) << 4))) = vv;
        }
        if (tid < 64) mLds[tid] = mask[b*S_ + s0 + tid];
        __syncthreads();

        // S^T[s][q]
        f32x4 st[4];
#pragma unroll
        for (int mf = 0; mf < 4; mf++) st[mf] = (f32x4){0.f, 0.f, 0.f, 0.f};
#pragma unroll
        for (int mf = 0; mf < 4; mf++) {
            const int srw = mf*16 + c;
            bf16x8 ak0 = *(const bf16x8*)(Ks + srw*128 + ((g*16)      ^ ((c & 7) << 4)));
            bf16x8 ak1 = *(const bf16x8*)(Ks + srw*128 + ((64 + g*16) ^ ((c & 7) << 4)));
            st[mf] = mfma16(ak0, bq0, st[mf]);
            st[mf] = mfma16(ak1, bq1, st[mf]);
        }

        // online softmax along s (per q-col c). lane holds s = 16*mf + 4*g + i.
        float sv[4][4];
        float tmax = -3.0e38f;
#pragma unroll
        for (int mf = 0; mf < 4; mf++) {
            const float4 mk = *(const float4*)(mLds + mf*16 + 4*g);
#pragma unroll
            for (int i = 0; i < 4; i++) {
                const float v = st[mf][i]*0.125f + (&mk.x)[i];
                sv[mf][i] = v;
                tmax = fmaxf(tmax, v);
            }
        }
        tmax = fmaxf(tmax, __shfl_xor(tmax, 16));
        tmax = fmaxf(tmax, __shfl_xor(tmax, 32));
        const float mnew = fmaxf(m_run, tmax);
        const float alpha = exp2f((m_run - mnew) * LOG2E);
        float p[4][4];
        float tsum = 0.f;
#pragma unroll
        for (int mf = 0; mf < 4; mf++)
#pragma unroll
            for (int i = 0; i < 4; i++) {
                const float e = exp2f((sv[mf][i] - mnew) * LOG2E);
                p[mf][i] = e;
                tsum += e;
            }
        tsum += __shfl_xor(tsum, 16);
        tsum += __shfl_xor(tsum, 32);
        l_run = l_run * alpha + tsum;
        m_run = mnew;
#pragma unroll
        for (int mf = 0; mf < 4; mf++)
#pragma unroll
            for (int i = 0; i < 4; i++) o[mf][i] *= alpha;

        // pack P to bf16 pairs (per frag: [i0|i1], [i2|i3])
        unsigned int ppk[4][2];
#pragma unroll
        for (int mf = 0; mf < 4; mf++) {
            ppk[mf][0] = (unsigned)f2bf(p[mf][0]) | ((unsigned)f2bf(p[mf][1]) << 16);
            ppk[mf][1] = (unsigned)f2bf(p[mf][2]) | ((unsigned)f2bf(p[mf][3]) << 16);
        }
        // PV: B-frag elem j of lane(g,c) = P^T[32ks + 8g + j][c]
        //   source lane = (2*(g&1) + (j>>2))*16 + c, source frag = 2ks + (g>>1), reg = j&3
#pragma unroll
        for (int ks = 0; ks < 2; ks++) {
            uint4v bw;
#pragma unroll
            for (int tp = 0; tp < 4; tp++) {
                const int src = (g & 1)*32 + (tp >> 1)*16 + c;
                const unsigned int lo = (unsigned int)__shfl((int)ppk[2*ks  ][tp & 1], src, 64);
                const unsigned int hi = (unsigned int)__shfl((int)ppk[2*ks+1][tp & 1], src, 64);
                bw[tp] = (g & 2) ? hi : lo;
            }
            const bf16x8 bp = __builtin_bit_cast(bf16x8, bw);
#pragma unroll
            for (int mf = 0; mf < 4; mf++) {
                const int drw = mf*16 + c;
                bf16x8 av = *(const bf16x8*)(Vs + drw*128 + ((ks*64 + g*16) ^ ((c & 7) << 4)));
                o[mf] = mfma16(av, bp, o[mf]);
            }
        }
        __syncthreads();
    }

    // epilogue: O^T frags -> LDS bounce (per-wave region, pitch 72 elems) -> coalesced store
    const float inv = 1.f / l_run;
    char* eb = smem + w * 2304;
#pragma unroll
    for (int mf = 0; mf < 4; mf++) {
        uint2 ww;
        ww.x = (unsigned)f2bf(o[mf][0]*inv) | ((unsigned)f2bf(o[mf][1]*inv) << 16);
        ww.y = (unsigned)f2bf(o[mf][2]*inv) | ((unsigned)f2bf(o[mf][3]*inv) << 16);
        *(uint2*)(eb + c*144 + mf*32 + 8*g) = ww;   // row q=c, d = mf*16 + 4g
    }
    asm volatile("s_waitcnt lgkmcnt(0)" ::: "memory");
    const int ql = lane >> 2, dseg = lane & 3;
    uint4 r0 = *(const uint4*)(eb + ql*144 + dseg*32);
    uint4 r1 = *(const uint4*)(eb + ql*144 + dseg*32 + 16);
    unsigned short* op = Octx + (size_t)(b*T_ + q0 + w*16 + ql)*H_ + h*64 + dseg*16;
    *(uint4*)op = r0;
    *(uint4*)(op + 8) = r1;
}

// ---------------- residual + LayerNorm ----------------
template<int OUTMODE>   // 0: bf16 out, 1: f32 out
__global__ __launch_bounds__(256)
void ln_kernel(const unsigned short* __restrict__ resid,
               const unsigned short* __restrict__ proj,
               const float* __restrict__ gam,
               const float* __restrict__ bet,
               unsigned short* __restrict__ obf,
               float* __restrict__ of32)
{
    __shared__ float red[8];
    const int tid = threadIdx.x;
    const int lane = tid & 63, w = tid >> 6;
    const int i = tid * 4;
    const size_t base = (size_t)blockIdx.x * 1024 + i;
    uint2 rv = *(const uint2*)(resid + base);
    uint2 pv = *(const uint2*)(proj + base);
    float x[4];
    x[0] = bf2f(rv.x & 0xffffu) + bf2f(pv.x & 0xffffu);
    x[1] = bf2f(rv.x >> 16)     + bf2f(pv.x >> 16);
    x[2] = bf2f(rv.y & 0xffffu) + bf2f(pv.y & 0xffffu);
    x[3] = bf2f(rv.y >> 16)     + bf2f(pv.y >> 16);
    float s = x[0] + x[1] + x[2] + x[3];
    float q = x[0]*x[0] + x[1]*x[1] + x[2]*x[2] + x[3]*x[3];
#pragma unroll
    for (int off = 1; off < 64; off <<= 1) {
        s += __shfl_xor(s, off);
        q += __shfl_xor(q, off);
    }
    if (lane == 0) { red[w*2] = s; red[w*2 + 1] = q; }
    __syncthreads();
    s = red[0] + red[2] + red[4] + red[6];
    q = red[1] + red[3] + red[5] + red[7];
    const float mu   = s * (1.f/1024.f);
    const float var  = q * (1.f/1024.f) - mu*mu;
    const float rstd = rsqrtf(var + 1e-12f);
    const float4 gv = *(const float4*)(gam + i);
    const float4 bv = *(const float4*)(bet + i);
    float y[4];
#pragma unroll
    for (int j = 0; j < 4; j++)
        y[j] = (x[j] - mu) * rstd * (&gv.x)[j] + (&bv.x)[j];
    if (OUTMODE == 0) {
        uint2 oo;
        oo.x = (unsigned)f2bf(y[0]) | ((unsigned)f2bf(y[1]) << 16);
        oo.y = (unsigned)f2bf(y[2]) | ((unsigned)f2bf(y[3]) << 16);
        *(uint2*)(obf + base) = oo;
    } else {
        float4 oo; oo.x = y[0]; oo.y = y[1]; oo.z = y[2]; oo.w = y[3];
        *(float4*)(of32 + base) = oo;
    }
}

extern "C" void kernel_launch(void* const* d_in, const int* in_sizes, int n_in,
                              void* d_out, int out_size, void* d_ws, size_t ws_size,
                              hipStream_t stream)
{
    const float* enc   = (const float*)d_in[0];
    const float* dec   = (const float*)d_in[1];
    const float* smask = (const float*)d_in[2];
    const float* tmask = (const float*)d_in[3];
    const float* Wq = (const float*)d_in[4];
    const float* bq = (const float*)d_in[5];
    const float* Wk = (const float*)d_in[6];
    const float* bk = (const float*)d_in[7];
    const float* Wv = (const float*)d_in[8];
    const float* bv = (const float*)d_in[9];
    const float* Wd = (const float*)d_in[10];
    const float* bd = (const float*)d_in[11];
    const float* lng = (const float*)d_in[12];
    const float* lnb = (const float*)d_in[13];
    float* out = (float*)d_out;

    char* ws = (char*)d_ws;
    const size_t MB = 1024ull * 1024ull;
    unsigned short* dec_bf = (unsigned short*)(ws + 0*MB);
    unsigned short* enc_bf = (unsigned short*)(ws + 8*MB);
    unsigned short* Wq_bf  = (unsigned short*)(ws + 16*MB);
    unsigned short* Wk_bf  = (unsigned short*)(ws + 18*MB);
    unsigned short* Wv_bf  = (unsigned short*)(ws + 20*MB);
    unsigned short* Wd_bf  = (unsigned short*)(ws + 22*MB);
    unsigned short* q1  = (unsigned short*)(ws + 24*MB);
    unsigned short* k1  = (unsigned short*)(ws + 32*MB);
    unsigned short* v1  = (unsigned short*)(ws + 40*MB);
    unsigned short* ek  = (unsigned short*)(ws + 48*MB);
    unsigned short* ev  = (unsigned short*)(ws + 56*MB);
    unsigned short* vt1 = (unsigned short*)(ws + 64*MB);
    unsigned short* ctx      = dec_bf;  // dec_bf dead after QKV gemm
    unsigned short* proj     = enc_bf;  // enc_bf dead after EKV gemm
    unsigned short* self_out = k1;      // k1 dead after attn1
    unsigned short* evt      = v1;      // v1 dead after its transpose

    cvt_bf16<<<4096, 256, 0, stream>>>(dec, dec_bf, 1048576);
    cvt_bf16<<<4096, 256, 0, stream>>>(enc, enc_bf, 1048576);
    cvt_bf16<<<1024, 256, 0, stream>>>(Wq, Wq_bf, 262144);
    cvt_bf16<<<1024, 256, 0, stream>>>(Wk, Wk_bf, 262144);
    cvt_bf16<<<1024, 256, 0, stream>>>(Wv, Wv_bf, 262144);
    cvt_bf16<<<1024, 256, 0, stream>>>(Wd, Wd_bf, 262144);

    // q1,k1,v1 = dec @ {Wq,Wk,Wv}^T + b   (fused, grid.y selects weight)
    gemm_bf16<<<dim3(32, 24), 256, 0, stream>>>(dec_bf, Wq_bf, Wk_bf, Wv_bf, bq, bk, bv, q1, k1, v1);
    // ek,ev = enc @ {Wk,Wv}^T + b
    gemm_bf16<<<dim3(32, 16), 256, 0, stream>>>(enc_bf, Wk_bf, Wv_bf, Wv_bf, bk, bv, bv, ek, ev, ev);

    transpose_v<<<dim3(16, 64), 256, 0, stream>>>(v1, vt1);
    transpose_v<<<dim3(16, 64), 256, 0, stream>>>(ev, evt);

    // self-attention
    attn_fused<<<dim3(16, 64), 256, 0, stream>>>(q1, k1, vt1, tmask, ctx);
    gemm_bf16<<<dim3(32, 8), 256, 0, stream>>>(ctx, Wd_bf, Wd_bf, Wd_bf, bd, bd, bd, proj, proj, proj);
    ln_kernel<0><<<4096, 256, 0, stream>>>(q1, proj, lng, lnb, self_out, nullptr);

    // cross-attention (query = self_out directly)
    attn_fused<<<dim3(16, 64), 256, 0, stream>>>(self_out, ek, evt, smask, ctx);
    gemm_bf16<<<dim3(32, 8), 256, 0, stream>>>(ctx, Wd_bf, Wd_bf, Wd_bf, bd, bd, bd, proj, proj, proj);
    ln_kernel<1><<<4096, 256, 0, stream>>>(self_out, proj, lng, lnb, nullptr, out);
}

// Round 2
// 195.160 us; speedup vs baseline: 1.2887x; 1.2887x over previous
//
#include <hip/hip_runtime.h>
#include <stdint.h>

// AlbertSeq2Seq fused pipeline, bf16 MFMA implementation. Round 2:
// attention rebuilt on 32x32x16 MFMA, swapped-QK^T in-register softmax
// (log2-domain, K pre-scaled by 0.125*log2e), cvt_pk+permlane32_swap P->A-frag.
// Shapes: B=4, T=S=1024, H=1024, heads=16, d=64.

#define B_   4
#define T_   1024
#define S_   1024
#define H_   1024
#define LOG2E 1.44269504088896340736f
#define SCALE_K (0.125f * LOG2E)

typedef __attribute__((ext_vector_type(8)))  __bf16       bf16x8;
typedef __attribute__((ext_vector_type(4)))  float        f32x4;
typedef __attribute__((ext_vector_type(16))) float        f32x16;
typedef __attribute__((ext_vector_type(4)))  unsigned int uint4v;

static __device__ __forceinline__ float bf2f(unsigned int u) {
    return __builtin_bit_cast(float, u << 16);
}
static __device__ __forceinline__ unsigned short f2bf(float f) {
    unsigned int x = __builtin_bit_cast(unsigned int, f);
    return (unsigned short)((x + 0x7fffu + ((x >> 16) & 1u)) >> 16);
}
static __device__ __forceinline__ unsigned int cvt_pk_bf16(float lo, float hi) {
    unsigned int r;
    asm("v_cvt_pk_bf16_f32 %0, %1, %2" : "=v"(r) : "v"(lo), "v"(hi));
    return r;
}
// swaps: a's hi lanes <-> b's lo lanes. After: a = frag-word for all lanes (own lo / partner-b hi),
// b = (partner-a lo / own b hi).
static __device__ __forceinline__ void perm32swap(unsigned int& a, unsigned int& b) {
    asm("v_permlane32_swap_b32 %0, %1" : "+v"(a), "+v"(b));
}
static __device__ __forceinline__ f32x4 mfma16(bf16x8 a, bf16x8 b, f32x4 c) {
    return __builtin_amdgcn_mfma_f32_16x16x32_bf16(a, b, c, 0, 0, 0);
}
static __device__ __forceinline__ f32x16 mfma32(bf16x8 a, bf16x8 b, f32x16 c) {
    return __builtin_amdgcn_mfma_f32_32x32x16_bf16(a, b, c, 0, 0, 0);
}

typedef const __attribute__((address_space(1))) void gv_t;
typedef __attribute__((address_space(3))) void lv_t;
static __device__ __forceinline__ void g2lds16(const void* g, void* l) {
    __builtin_amdgcn_global_load_lds((gv_t*)(size_t)g, (lv_t*)(unsigned int)(size_t)l, 16, 0, 0);
}

// ---------------- fused fp32 -> bf16 convert (6 tensors, 1 launch) ----------------
struct CvtArgs {
    const float* src[6];
    unsigned short* dst[6];
    float scale[6];
    int n4[6];
};
__global__ __launch_bounds__(256)
void cvt_multi(CvtArgs a) {
    const int k = blockIdx.y;
    const int i = blockIdx.x * 256 + threadIdx.x;
    if (i >= a.n4[k]) return;
    const float s = a.scale[k];
    float4 v = ((const float4*)a.src[k])[i];
    uint2 o;
    o.x = (unsigned)f2bf(v.x * s) | ((unsigned)f2bf(v.y * s) << 16);
    o.y = (unsigned)f2bf(v.z * s) | ((unsigned)f2bf(v.w * s) << 16);
    ((uint2*)a.dst[k])[i] = o;
}

// ---------------- GEMM: C = A @ W^T + bias*bscale, all [*,1024] row-major bf16 ----------------
__global__ __launch_bounds__(256, 2)
void gemm_bf16(const unsigned short* __restrict__ A,
               const unsigned short* __restrict__ W0,
               const unsigned short* __restrict__ W1,
               const unsigned short* __restrict__ W2,
               const float* __restrict__ bias0,
               const float* __restrict__ bias1,
               const float* __restrict__ bias2,
               float bs0, float bs1, float bs2,
               unsigned short* __restrict__ O0,
               unsigned short* __restrict__ O1,
               unsigned short* __restrict__ O2)
{
    __shared__ char smem[16384];
    char* As = smem;
    char* Bs = smem + 8192;
    const int tid = threadIdx.x;
    const int lane = tid & 63;
    const int w = tid >> 6;
    const int c = lane & 15, g = lane >> 4;
    const int wm = (w >> 1) * 64, wn = (w & 1) * 64;
    const int m0 = blockIdx.x * 128;
    const int ysel = blockIdx.y >> 3;
    const int n0 = (blockIdx.y & 7) * 128;
    const unsigned short* W = (ysel == 0) ? W0 : ((ysel == 1) ? W1 : W2);
    const float* bias        = (ysel == 0) ? bias0 : ((ysel == 1) ? bias1 : bias2);
    const float bscale       = (ysel == 0) ? bs0 : ((ysel == 1) ? bs1 : bs2);
    unsigned short* O        = (ysel == 0) ? O0 : ((ysel == 1) ? O1 : O2);

    f32x4 acc[4][4];
#pragma unroll
    for (int i = 0; i < 4; i++)
#pragma unroll
        for (int j = 0; j < 4; j++) acc[i][j] = (f32x4){0.f, 0.f, 0.f, 0.f};

    const int srow = w * 16 + (lane >> 2);
    const int scol = (lane & 3) * 8;
    const unsigned short* gA = A + (size_t)(m0 + srow) * 1024 + scol;
    const unsigned short* gB = W + (size_t)(n0 + srow) * 1024 + scol;
    char* lA = As + w * 1024;
    char* lB = Bs + w * 1024;

    for (int kk = 0; kk < 1024; kk += 32) {
        g2lds16(gA + kk,           lA);
        g2lds16(gA + kk + 64*1024, lA + 4096);
        g2lds16(gB + kk,           lB);
        g2lds16(gB + kk + 64*1024, lB + 4096);
        __syncthreads();
        bf16x8 af[4], bfr[4];
#pragma unroll
        for (int t = 0; t < 4; t++) {
            af[t]  = *(const bf16x8*)(As + (wm + t*16 + c)*64 + g*16);
            bfr[t] = *(const bf16x8*)(Bs + (wn + t*16 + c)*64 + g*16);
        }
#pragma unroll
        for (int i = 0; i < 4; i++)
#pragma unroll
            for (int j = 0; j < 4; j++)
                acc[i][j] = mfma16(af[i], bfr[j], acc[i][j]);
        __syncthreads();
    }

    float bv[4];
#pragma unroll
    for (int j = 0; j < 4; j++) bv[j] = bias[n0 + wn + j*16 + c] * bscale;
#pragma unroll
    for (int i = 0; i < 4; i++) {
        const int mrow = m0 + wm + i*16 + g*4;
#pragma unroll
        for (int r = 0; r < 4; r++) {
            unsigned short* orow = O + (size_t)(mrow + r) * 1024 + n0 + wn + c;
#pragma unroll
            for (int j = 0; j < 4; j++)
                orow[j*16] = f2bf(acc[i][j][r] + bv[j]);
        }
    }
}

// ---------------- per-head V transpose: V[b,s,h*64+d] -> VT[(b*16+h)*64+d][s] ----------------
__global__ __launch_bounds__(256)
void transpose_v(const unsigned short* __restrict__ V, unsigned short* __restrict__ VT)
{
    __shared__ char sm[8192];
    const int tid = threadIdx.x;
    const int bh = blockIdx.y, b = bh >> 4, h = bh & 15;
    const int s0 = blockIdx.x * 64;
    for (int u = tid; u < 512; u += 256) {
        const int r = u >> 3, sg = u & 7;
        uint4 v = *(const uint4*)(V + (size_t)(b*S_ + s0 + r)*H_ + h*64 + sg*8);
        *(uint4*)(sm + r*128 + ((sg*16) ^ ((r & 7) << 4))) = v;
    }
    __syncthreads();
    const int d = tid >> 2, ss = tid & 3;
    unsigned int ow[8];
#pragma unroll
    for (int j2 = 0; j2 < 8; j2++) {
        const int s_a = ss*16 + 2*j2, s_b = s_a + 1;
        unsigned int ta = *(const unsigned short*)(sm + s_a*128 + ((2*d) ^ ((s_a & 7) << 4)));
        unsigned int tb = *(const unsigned short*)(sm + s_b*128 + ((2*d) ^ ((s_b & 7) << 4)));
        ow[j2] = ta | (tb << 16);
    }
    unsigned short* op = VT + (size_t)(bh*64 + d)*S_ + s0 + ss*16;
    uint4 o0, o1;
    o0.x = ow[0]; o0.y = ow[1]; o0.z = ow[2]; o0.w = ow[3];
    o1.x = ow[4]; o1.y = ow[5]; o1.z = ow[6]; o1.w = ow[7];
    *(uint4*)op = o0;
    *(uint4*)(op + 8) = o1;
}

// ---------------- fused flash attention, 32x32 m214-style ----------------
// grid (T/128, B*NH), 256 threads = 4 waves, wave owns 32 q-rows.
// K arrives pre-scaled by 0.125*log2e  ->  P = exp2(S^T) directly (fixed-shift softmax).
// S^T = mfma32(A=K, B=Q): C col = q = lane&31, rows s = (r&3)+8*(r>>2)+4*(lane>>5).
// PV:  O = mfma32(A=P, B=V): A row = q = lane&31 (already lane-local!), k = s.
__global__ __launch_bounds__(256, 4)
void attn_fused2(const unsigned short* __restrict__ Q,
                 const unsigned short* __restrict__ Kx,
                 const unsigned short* __restrict__ VT,
                 const float* __restrict__ mask,
                 unsigned short* __restrict__ Octx)
{
    __shared__ char smem[8192*2 + 4096 + 512 + 16];
    char* Ks    = smem;                         // [64 s][64 d] XOR-swizzled rows
    char* Vs    = smem + 8192;                  // [64 d][64 s] XOR-swizzled rows
    float* mb   = (float*)(smem + 16384);       // 1024 mask*LOG2E
    float* lbuf = (float*)(smem + 16384 + 4096);// 4 waves x 32 linv
    int* flag   = (int*)(smem + 16384 + 4096 + 512);

    const int tid = threadIdx.x;
    const int lane = tid & 63, w = tid >> 6;
    const int qc = lane & 31, hi = lane >> 5;
    const int bh = blockIdx.y, b = bh >> 4, h = bh & 15;
    const int q0 = blockIdx.x * 128 + w * 32;

    // staging addressing: u in {tid, tid+256} -> row = u>>3 (64), 16B seg = u&7
    const int r0 = tid >> 3, sg = tid & 7;
    const unsigned short* gK0 = Kx + (size_t)(b*S_ + r0)*H_      + h*64 + sg*8;
    const unsigned short* gK1 = gK0 + (size_t)32*H_;
    const unsigned short* gV0 = VT + (size_t)(bh*64 + r0)*S_     + sg*8;
    const unsigned short* gV1 = gV0 + (size_t)32*S_;
    const int swz = (sg*16) ^ ((r0 & 7) << 4);
    char* lK0 = Ks + r0*128 + swz;
    char* lV0 = Vs + r0*128 + swz;

    // Q fragments: B[k=d][col=q], k = hi*8 + j within each 16-d step
    const unsigned short* qptr = Q + (size_t)(b*T_ + q0 + qc)*H_ + h*64 + hi*8;
    bf16x8 qf[4];
#pragma unroll
    for (int s = 0; s < 4; s++) qf[s] = *(const bf16x8*)(qptr + s*16);

    // tile 0 staging loads (issued early)
    uint4 cK0 = *(const uint4*)gK0;
    uint4 cK1 = *(const uint4*)gK1;
    uint4 cV0 = *(const uint4*)gV0;
    uint4 cV1 = *(const uint4*)gV1;

    if (tid == 0) *flag = 0;
    __syncthreads();
    {
        float4 mv = ((const float4*)(mask + (size_t)b*S_))[tid];
        float4 ms;
        ms.x = mv.x * LOG2E; ms.y = mv.y * LOG2E; ms.z = mv.z * LOG2E; ms.w = mv.w * LOG2E;
        ((float4*)mb)[tid] = ms;
        if (mv.x != 0.f || mv.y != 0.f || mv.z != 0.f || mv.w != 0.f) atomicOr(flag, 1);
    }
    *(uint4*)lK0          = cK0;
    *(uint4*)(lK0 + 4096) = cK1;
    *(uint4*)lV0          = cV0;
    *(uint4*)(lV0 + 4096) = cV1;
    __syncthreads();
    const int msk = *flag;

    f32x16 o0 = {}, o1 = {};
    float lacc = 0.f;

    for (int t = 0; t < 16; ++t) {
        // T14: issue next tile's loads before compute
        uint4 nK0, nK1, nV0, nV1;
        if (t < 15) {
            const size_t ko = (size_t)(t + 1) * 64 * H_;
            const int    vo = (t + 1) * 64;
            nK0 = *(const uint4*)(gK0 + ko);
            nK1 = *(const uint4*)(gK1 + ko);
            nV0 = *(const uint4*)(gV0 + vo);
            nV1 = *(const uint4*)(gV1 + vo);
        }

#pragma unroll
        for (int ts = 0; ts < 2; ++ts) {
            // ---- QK^T: 4 mfma over d ----
            f32x16 st = {};
            __builtin_amdgcn_s_setprio(1);
#pragma unroll
            for (int step = 0; step < 4; ++step) {
                bf16x8 ak = *(const bf16x8*)(Ks + (ts*32 + qc)*128 +
                             ((step*32 + hi*16) ^ ((qc & 7) << 4)));
                st = mfma32(ak, qf[step], st);
            }
            __builtin_amdgcn_s_setprio(0);

            // ---- softmax: P = exp2(S + mask*LOG2E), fixed shift ----
            float pv[16];
            if (msk) {
#pragma unroll
                for (int rq = 0; rq < 4; ++rq) {
                    const float4 bb = *(const float4*)(mb + t*64 + ts*32 + rq*8 + hi*4);
#pragma unroll
                    for (int e = 0; e < 4; ++e)
                        pv[rq*4 + e] = __builtin_amdgcn_exp2f(st[rq*4 + e] + (&bb.x)[e]);
                }
            } else {
#pragma unroll
                for (int r = 0; r < 16; ++r) pv[r] = __builtin_amdgcn_exp2f(st[r]);
            }
#pragma unroll
            for (int r = 0; r < 16; ++r) lacc += pv[r];

            // ---- P -> A-frags (T12) + PV, per 16-s subtile ----
#pragma unroll
            for (int half = 0; half < 2; ++half) {      // regs r = half*8 .. +7, ks = ts*2+half
                unsigned w0 = cvt_pk_bf16(pv[half*8 + 0], pv[half*8 + 1]);
                unsigned w1 = cvt_pk_bf16(pv[half*8 + 2], pv[half*8 + 3]);
                unsigned w2 = cvt_pk_bf16(pv[half*8 + 4], pv[half*8 + 5]);
                unsigned w3 = cvt_pk_bf16(pv[half*8 + 6], pv[half*8 + 7]);
                perm32swap(w0, w2);
                perm32swap(w1, w3);
                uint4v fw; fw[0] = w0; fw[1] = w1; fw[2] = w2; fw[3] = w3;
                const bf16x8 pa = __builtin_bit_cast(bf16x8, fw);
                const int scol = (ts*64 + half*32 + hi*16) ^ ((qc & 7) << 4);
                bf16x8 v0 = *(const bf16x8*)(Vs + qc*128        + scol);
                bf16x8 v1 = *(const bf16x8*)(Vs + (32 + qc)*128 + scol);
                __builtin_amdgcn_s_setprio(1);
                o0 = mfma32(pa, v0, o0);
                o1 = mfma32(pa, v1, o1);
                __builtin_amdgcn_s_setprio(0);
            }
        }

        __syncthreads();
        if (t < 15) {
            *(uint4*)lK0          = nK0;
            *(uint4*)(lK0 + 4096) = nK1;
            *(uint4*)lV0          = nV0;
            *(uint4*)(lV0 + 4096) = nV1;
        }
        __syncthreads();
    }

    // ---- epilogue: l reduce (own + partner), normalize, store ----
    {
        unsigned la = __builtin_bit_cast(unsigned, lacc);
        unsigned lb = la;
        perm32swap(la, lb);
        const float ltot = __builtin_bit_cast(float, la) + __builtin_bit_cast(float, lb);
        const float linv = 1.f / ltot;
        if (hi == 0) lbuf[w*32 + qc] = linv;
    }
    __syncthreads();
    float4 li[4];
#pragma unroll
    for (int rq = 0; rq < 4; ++rq)
        li[rq] = *(const float4*)(lbuf + w*32 + rq*8 + hi*4);

#pragma unroll
    for (int dt = 0; dt < 2; ++dt) {
        const f32x16& oo = dt ? o1 : o0;
#pragma unroll
        for (int r = 0; r < 16; ++r) {
            const int qrow = (r & 3) + 8*(r >> 2) + 4*hi;
            const float val = oo[r] * (&li[r >> 2].x)[r & 3];
            Octx[(size_t)(b*T_ + q0 + qrow)*H_ + h*64 + dt*32 + qc] = f2bf(val);
        }
    }
}

// ---------------- residual + LayerNorm ----------------
template<int OUTMODE>   // 0: bf16 out, 1: f32 out
__global__ __launch_bounds__(256)
void ln_kernel(const unsigned short* __restrict__ resid,
               const unsigned short* __restrict__ proj,
               const float* __restrict__ gam,
               const float* __restrict__ bet,
               unsigned short* __restrict__ obf,
               float* __restrict__ of32)
{
    __shared__ float red[8];
    const int tid = threadIdx.x;
    const int lane = tid & 63, w = tid >> 6;
    const int i = tid * 4;
    const size_t base = (size_t)blockIdx.x * 1024 + i;
    uint2 rv = *(const uint2*)(resid + base);
    uint2 pv = *(const uint2*)(proj + base);
    float x[4];
    x[0] = bf2f(rv.x & 0xffffu) + bf2f(pv.x & 0xffffu);
    x[1] = bf2f(rv.x >> 16)     + bf2f(pv.x >> 16);
    x[2] = bf2f(rv.y & 0xffffu) + bf2f(pv.y & 0xffffu);
    x[3] = bf2f(rv.y >> 16)     + bf2f(pv.y >> 16);
    float s = x[0] + x[1] + x[2] + x[3];
    float q = x[0]*x[0] + x[1]*x[1] + x[2]*x[2] + x[3]*x[3];
#pragma unroll
    for (int off = 1; off < 64; off <<= 1) {
        s += __shfl_xor(s, off);
        q += __shfl_xor(q, off);
    }
    if (lane == 0) { red[w*2] = s; red[w*2 + 1] = q; }
    __syncthreads();
    s = red[0] + red[2] + red[4] + red[6];
    q = red[1] + red[3] + red[5] + red[7];
    const float mu   = s * (1.f/1024.f);
    const float var  = q * (1.f/1024.f) - mu*mu;
    const float rstd = rsqrtf(var + 1e-12f);
    const float4 gv = *(const float4*)(gam + i);
    const float4 bv = *(const float4*)(bet + i);
    float y[4];
#pragma unroll
    for (int j = 0; j < 4; j++)
        y[j] = (x[j] - mu) * rstd * (&gv.x)[j] + (&bv.x)[j];
    if (OUTMODE == 0) {
        uint2 oo;
        oo.x = (unsigned)f2bf(y[0]) | ((unsigned)f2bf(y[1]) << 16);
        oo.y = (unsigned)f2bf(y[2]) | ((unsigned)f2bf(y[3]) << 16);
        *(uint2*)(obf + base) = oo;
    } else {
        float4 oo; oo.x = y[0]; oo.y = y[1]; oo.z = y[2]; oo.w = y[3];
        *(float4*)(of32 + base) = oo;
    }
}

extern "C" void kernel_launch(void* const* d_in, const int* in_sizes, int n_in,
                              void* d_out, int out_size, void* d_ws, size_t ws_size,
                              hipStream_t stream)
{
    const float* enc   = (const float*)d_in[0];
    const float* dec   = (const float*)d_in[1];
    const float* smask = (const float*)d_in[2];
    const float* tmask = (const float*)d_in[3];
    const float* Wq = (const float*)d_in[4];
    const float* bq = (const float*)d_in[5];
    const float* Wk = (const float*)d_in[6];
    const float* bk = (const float*)d_in[7];
    const float* Wv = (const float*)d_in[8];
    const float* bv = (const float*)d_in[9];
    const float* Wd = (const float*)d_in[10];
    const float* bd = (const float*)d_in[11];
    const float* lng = (const float*)d_in[12];
    const float* lnb = (const float*)d_in[13];
    float* out = (float*)d_out;

    char* ws = (char*)d_ws;
    const size_t MB = 1024ull * 1024ull;
    unsigned short* dec_bf = (unsigned short*)(ws + 0*MB);
    unsigned short* enc_bf = (unsigned short*)(ws + 8*MB);
    unsigned short* Wq_bf  = (unsigned short*)(ws + 16*MB);
    unsigned short* Wk_bf  = (unsigned short*)(ws + 18*MB);
    unsigned short* Wv_bf  = (unsigned short*)(ws + 20*MB);
    unsigned short* Wd_bf  = (unsigned short*)(ws + 22*MB);
    unsigned short* q1  = (unsigned short*)(ws + 24*MB);
    unsigned short* k1  = (unsigned short*)(ws + 32*MB);
    unsigned short* v1  = (unsigned short*)(ws + 40*MB);
    unsigned short* ek  = (unsigned short*)(ws + 48*MB);
    unsigned short* ev  = (unsigned short*)(ws + 56*MB);
    unsigned short* vt1 = (unsigned short*)(ws + 64*MB);
    unsigned short* ctx      = dec_bf;
    unsigned short* proj     = enc_bf;
    unsigned short* self_out = k1;
    unsigned short* evt      = v1;

    CvtArgs ca;
    ca.src[0] = dec; ca.dst[0] = dec_bf; ca.scale[0] = 1.f;      ca.n4[0] = 1048576;
    ca.src[1] = enc; ca.dst[1] = enc_bf; ca.scale[1] = 1.f;      ca.n4[1] = 1048576;
    ca.src[2] = Wq;  ca.dst[2] = Wq_bf;  ca.scale[2] = 1.f;      ca.n4[2] = 262144;
    ca.src[3] = Wk;  ca.dst[3] = Wk_bf;  ca.scale[3] = SCALE_K;  ca.n4[3] = 262144;
    ca.src[4] = Wv;  ca.dst[4] = Wv_bf;  ca.scale[4] = 1.f;      ca.n4[4] = 262144;
    ca.src[5] = Wd;  ca.dst[5] = Wd_bf;  ca.scale[5] = 1.f;      ca.n4[5] = 262144;
    cvt_multi<<<dim3(4096, 6), 256, 0, stream>>>(ca);

    // q1,k1,v1 = dec @ {Wq,Wk,Wv}^T + b  (k1 pre-scaled by 0.125*log2e via Wk/bk fold)
    gemm_bf16<<<dim3(32, 24), 256, 0, stream>>>(dec_bf, Wq_bf, Wk_bf, Wv_bf,
                                                bq, bk, bv, 1.f, SCALE_K, 1.f, q1, k1, v1);
    // ek,ev = enc @ {Wk,Wv}^T + b
    gemm_bf16<<<dim3(32, 16), 256, 0, stream>>>(enc_bf, Wk_bf, Wv_bf, Wv_bf,
                                                bk, bv, bv, SCALE_K, 1.f, 1.f, ek, ev, ev);

    transpose_v<<<dim3(16, 64), 256, 0, stream>>>(v1, vt1);
    transpose_v<<<dim3(16, 64), 256, 0, stream>>>(ev, evt);

    // self-attention
    attn_fused2<<<dim3(8, 64), 256, 0, stream>>>(q1, k1, vt1, tmask, ctx);
    gemm_bf16<<<dim3(32, 8), 256, 0, stream>>>(ctx, Wd_bf, Wd_bf, Wd_bf,
                                               bd, bd, bd, 1.f, 1.f, 1.f, proj, proj, proj);
    ln_kernel<0><<<4096, 256, 0, stream>>>(q1, proj, lng, lnb, self_out, nullptr);

    // cross-attention (query = self_out directly)
    attn_fused2<<<dim3(8, 64), 256, 0, stream>>>(self_out, ek, evt, smask, ctx);
    gemm_bf16<<<dim3(32, 8), 256, 0, stream>>>(ctx, Wd_bf, Wd_bf, Wd_bf,
                                               bd, bd, bd, 1.f, 1.f, 1.f, proj, proj, proj);
    ln_kernel<1><<<4096, 256, 0, stream>>>(self_out, proj, lng, lnb, nullptr, out);
}

// Round 3
// 176.371 us; speedup vs baseline: 1.4259x; 1.1065x over previous
//
#include <hip/hip_runtime.h>
#include <stdint.h>

// AlbertSeq2Seq fused pipeline, bf16 MFMA. Round 3:
//  - GEMM: BK=64 (half the barriers), seg-XOR swizzled LDS (128B rows),
//    LDS-bounce coalesced epilogue, QKV+EKV merged into one launch (5 sets).
//  - Attention: double-buffered K/V LDS -> single barrier per tile.
// Shapes: B=4, T=S=1024, H=1024, heads=16, d=64.

#define B_   4
#define T_   1024
#define S_   1024
#define H_   1024
#define LOG2E 1.44269504088896340736f
#define SCALE_K (0.125f * LOG2E)

typedef __attribute__((ext_vector_type(8)))  __bf16       bf16x8;
typedef __attribute__((ext_vector_type(4)))  float        f32x4;
typedef __attribute__((ext_vector_type(16))) float        f32x16;
typedef __attribute__((ext_vector_type(4)))  unsigned int uint4v;

static __device__ __forceinline__ float bf2f(unsigned int u) {
    return __builtin_bit_cast(float, u << 16);
}
static __device__ __forceinline__ unsigned short f2bf(float f) {
    unsigned int x = __builtin_bit_cast(unsigned int, f);
    return (unsigned short)((x + 0x7fffu + ((x >> 16) & 1u)) >> 16);
}
static __device__ __forceinline__ unsigned int cvt_pk_bf16(float lo, float hi) {
    unsigned int r;
    asm("v_cvt_pk_bf16_f32 %0, %1, %2" : "=v"(r) : "v"(lo), "v"(hi));
    return r;
}
static __device__ __forceinline__ void perm32swap(unsigned int& a, unsigned int& b) {
    asm("v_permlane32_swap_b32 %0, %1" : "+v"(a), "+v"(b));
}
static __device__ __forceinline__ f32x4 mfma16(bf16x8 a, bf16x8 b, f32x4 c) {
    return __builtin_amdgcn_mfma_f32_16x16x32_bf16(a, b, c, 0, 0, 0);
}
static __device__ __forceinline__ f32x16 mfma32(bf16x8 a, bf16x8 b, f32x16 c) {
    return __builtin_amdgcn_mfma_f32_32x32x16_bf16(a, b, c, 0, 0, 0);
}

typedef const __attribute__((address_space(1))) void gv_t;
typedef __attribute__((address_space(3))) void lv_t;
static __device__ __forceinline__ void g2lds16(const void* g, void* l) {
    __builtin_amdgcn_global_load_lds((gv_t*)(size_t)g, (lv_t*)(unsigned int)(size_t)l, 16, 0, 0);
}

// ---------------- fused fp32 -> bf16 convert (6 tensors, 1 launch) ----------------
struct CvtArgs {
    const float* src[6];
    unsigned short* dst[6];
    float scale[6];
    int n4[6];
};
__global__ __launch_bounds__(256)
void cvt_multi(CvtArgs a) {
    const int k = blockIdx.y;
    const int i = blockIdx.x * 256 + threadIdx.x;
    if (i >= a.n4[k]) return;
    const float s = a.scale[k];
    float4 v = ((const float4*)a.src[k])[i];
    uint2 o;
    o.x = (unsigned)f2bf(v.x * s) | ((unsigned)f2bf(v.y * s) << 16);
    o.y = (unsigned)f2bf(v.z * s) | ((unsigned)f2bf(v.w * s) << 16);
    ((uint2*)a.dst[k])[i] = o;
}

// ---------------- GEMM: O[set] = A[set] @ W[set]^T + bias[set]*bs[set] ----------------
// 128x128 tile, BK=64, 4 waves (2x2), each wave 64x64 = 4x4 frags of 16x16x32.
// LDS [128 rows][64 elems = 128B], seg-XOR swizzle: LDS[row][s] = G[row][s ^ (row&7)]
// applied via pre-swizzled GLOBAL source (global_load_lds writes linearly).
// blockIdx.y: set = y>>3, n0 = (y&7)*128.
struct GemmJob {
    const unsigned short* A[5];
    const unsigned short* W[5];
    const float* bias[5];
    float bs[5];
    unsigned short* O[5];
};
__global__ __launch_bounds__(256, 2)
void gemm_bf16(GemmJob job)
{
    __shared__ char smem[32768];
    char* As = smem;
    char* Bs = smem + 16384;
    const int tid = threadIdx.x;
    const int lane = tid & 63;
    const int w = tid >> 6;
    const int c = lane & 15, g = lane >> 4;
    const int wm = (w >> 1) * 64, wn = (w & 1) * 64;
    const int m0 = blockIdx.x * 128;
    const int set = blockIdx.y >> 3;
    const int n0 = (blockIdx.y & 7) * 128;
    const unsigned short* A    = job.A[set];
    const unsigned short* W    = job.W[set];
    const float* bias          = job.bias[set];
    const float bscale         = job.bs[set];
    unsigned short* O          = job.O[set];

    f32x4 acc[4][4];
#pragma unroll
    for (int i = 0; i < 4; i++)
#pragma unroll
        for (int j = 0; j < 4; j++) acc[i][j] = (f32x4){0.f, 0.f, 0.f, 0.f};

    // staging: wave w covers rows [w*32, w*32+32); lane -> (row=+q*8+(l>>3), seg=l&7)
    // source col pre-swizzled: seg' = (l&7) ^ (l>>3)  (== (l&7) ^ (row&7))
    const int srow = w * 32 + (lane >> 3);
    const int swzc = ((lane & 7) ^ (lane >> 3)) * 8;
    const unsigned short* gA = A + (size_t)(m0 + srow) * 1024 + swzc;
    const unsigned short* gB = W + (size_t)(n0 + srow) * 1024 + swzc;
    char* lA = As + w * 4096;
    char* lB = Bs + w * 4096;

    for (int kk = 0; kk < 1024; kk += 64) {
#pragma unroll
        for (int q = 0; q < 4; q++) {
            g2lds16(gA + kk + q*8192, lA + q*1024);
            g2lds16(gB + kk + q*8192, lB + q*1024);
        }
        __syncthreads();
#pragma unroll
        for (int ksub = 0; ksub < 2; ksub++) {
            bf16x8 af[4], bfr[4];
#pragma unroll
            for (int t = 0; t < 4; t++) {
                const int ra = wm + t*16 + c;
                const int rb = wn + t*16 + c;
                const int so = ((ksub*4 + g) ^ (c & 7)) << 4;
                af[t]  = *(const bf16x8*)(As + ra*128 + so);
                bfr[t] = *(const bf16x8*)(Bs + rb*128 + so);
            }
#pragma unroll
            for (int i = 0; i < 4; i++)
#pragma unroll
                for (int j = 0; j < 4; j++)
                    acc[i][j] = mfma16(af[i], bfr[j], acc[i][j]);
        }
        __syncthreads();
    }

    // epilogue: per-wave LDS bounce (4KB region) -> coalesced dwordx4 stores
    float bvv[4];
#pragma unroll
    for (int j = 0; j < 4; j++) bvv[j] = bias[n0 + wn + j*16 + c] * bscale;
    char* eb = As + w * 4096;
#pragma unroll
    for (int p = 0; p < 2; p++) {
#pragma unroll
        for (int ii = 0; ii < 2; ii++) {
            const int i = p*2 + ii;
#pragma unroll
            for (int j = 0; j < 4; j++)
#pragma unroll
                for (int r = 0; r < 4; r++)
                    *(unsigned short*)(eb + (ii*16 + g*4 + r)*128 + (c + j*16)*2)
                        = f2bf(acc[i][j][r] + bvv[j]);
        }
        asm volatile("s_waitcnt lgkmcnt(0)" ::: "memory");
#pragma unroll
        for (int it = 0; it < 4; it++) {
            const int lrow = it*8 + (lane >> 3);
            uint4 vv = *(const uint4*)(eb + lrow*128 + (lane & 7)*16);
            *(uint4*)(O + (size_t)(m0 + wm + p*32 + lrow)*1024 + n0 + wn + (lane & 7)*8) = vv;
        }
        if (p == 0) asm volatile("s_waitcnt lgkmcnt(0)" ::: "memory");
    }
}

// ---------------- per-head V transpose: V[b,s,h*64+d] -> VT[(b*16+h)*64+d][s] ----------------
__global__ __launch_bounds__(256)
void transpose_v(const unsigned short* __restrict__ V, unsigned short* __restrict__ VT)
{
    __shared__ char sm[8192];
    const int tid = threadIdx.x;
    const int bh = blockIdx.y, b = bh >> 4, h = bh & 15;
    const int s0 = blockIdx.x * 64;
    for (int u = tid; u < 512; u += 256) {
        const int r = u >> 3, sg = u & 7;
        uint4 v = *(const uint4*)(V + (size_t)(b*S_ + s0 + r)*H_ + h*64 + sg*8);
        *(uint4*)(sm + r*128 + ((sg*16) ^ ((r & 7) << 4))) = v;
    }
    __syncthreads();
    const int d = tid >> 2, ss = tid & 3;
    unsigned int ow[8];
#pragma unroll
    for (int j2 = 0; j2 < 8; j2++) {
        const int s_a = ss*16 + 2*j2, s_b = s_a + 1;
        unsigned int ta = *(const unsigned short*)(sm + s_a*128 + ((2*d) ^ ((s_a & 7) << 4)));
        unsigned int tb = *(const unsigned short*)(sm + s_b*128 + ((2*d) ^ ((s_b & 7) << 4)));
        ow[j2] = ta | (tb << 16);
    }
    unsigned short* op = VT + (size_t)(bh*64 + d)*S_ + s0 + ss*16;
    uint4 o0, o1;
    o0.x = ow[0]; o0.y = ow[1]; o0.z = ow[2]; o0.w = ow[3];
    o1.x = ow[4]; o1.y = ow[5]; o1.z = ow[6]; o1.w = ow[7];
    *(uint4*)op = o0;
    *(uint4*)(op + 8) = o1;
}

// ---------------- fused flash attention, 32x32, double-buffered (1 barrier/tile) ----------------
// grid (T/128, B*NH), 256 threads = 4 waves, wave owns 32 q-rows.
// K pre-scaled by 0.125*log2e -> P = exp2(S^T) (fixed-shift softmax).
__global__ __launch_bounds__(256, 4)
void attn_fused2(const unsigned short* __restrict__ Q,
                 const unsigned short* __restrict__ Kx,
                 const unsigned short* __restrict__ VT,
                 const float* __restrict__ mask,
                 unsigned short* __restrict__ Octx)
{
    __shared__ char smem[32768 + 4096 + 512 + 16];
    float* mb   = (float*)(smem + 32768);
    float* lbuf = (float*)(smem + 32768 + 4096);
    int* flag   = (int*)(smem + 32768 + 4096 + 512);

    const int tid = threadIdx.x;
    const int lane = tid & 63, w = tid >> 6;
    const int qc = lane & 31, hi = lane >> 5;
    const int bh = blockIdx.y, b = bh >> 4, h = bh & 15;
    const int q0 = blockIdx.x * 128 + w * 32;

    const int r0 = tid >> 3, sg = tid & 7;
    const unsigned short* gK0 = Kx + (size_t)(b*S_ + r0)*H_  + h*64 + sg*8;
    const unsigned short* gK1 = gK0 + (size_t)32*H_;
    const unsigned short* gV0 = VT + (size_t)(bh*64 + r0)*S_ + sg*8;
    const unsigned short* gV1 = gV0 + (size_t)32*S_;
    const int woff = r0*128 + ((sg*16) ^ ((r0 & 7) << 4));

    const unsigned short* qptr = Q + (size_t)(b*T_ + q0 + qc)*H_ + h*64 + hi*8;
    bf16x8 qf[4];
#pragma unroll
    for (int s = 0; s < 4; s++) qf[s] = *(const bf16x8*)(qptr + s*16);

    // tile 0 staging
    uint4 cK0 = *(const uint4*)gK0;
    uint4 cK1 = *(const uint4*)gK1;
    uint4 cV0 = *(const uint4*)gV0;
    uint4 cV1 = *(const uint4*)gV1;

    if (tid == 0) *flag = 0;
    __syncthreads();
    {
        float4 mv = ((const float4*)(mask + (size_t)b*S_))[tid];
        float4 ms;
        ms.x = mv.x * LOG2E; ms.y = mv.y * LOG2E; ms.z = mv.z * LOG2E; ms.w = mv.w * LOG2E;
        ((float4*)mb)[tid] = ms;
        if (mv.x != 0.f || mv.y != 0.f || mv.z != 0.f || mv.w != 0.f) atomicOr(flag, 1);
    }
    {
        char* b0 = smem;
        *(uint4*)(b0 + woff)               = cK0;
        *(uint4*)(b0 + 4096 + woff)        = cK1;
        *(uint4*)(b0 + 8192 + woff)        = cV0;
        *(uint4*)(b0 + 8192 + 4096 + woff) = cV1;
    }
    __syncthreads();
    const int msk = *flag;

    f32x16 o0 = {}, o1 = {};
    float lacc = 0.f;

    for (int t = 0; t < 16; ++t) {
        uint4 nK0, nK1, nV0, nV1;
        if (t < 15) {
            const size_t ko = (size_t)(t + 1) * 64 * H_;
            const int    vo = (t + 1) * 64;
            nK0 = *(const uint4*)(gK0 + ko);
            nK1 = *(const uint4*)(gK1 + ko);
            nV0 = *(const uint4*)(gV0 + vo);
            nV1 = *(const uint4*)(gV1 + vo);
        }
        char* Ks = smem + (t & 1) * 16384;
        char* Vs = Ks + 8192;

#pragma unroll
        for (int ts = 0; ts < 2; ++ts) {
            // ---- QK^T ----
            f32x16 st = {};
            __builtin_amdgcn_s_setprio(1);
#pragma unroll
            for (int step = 0; step < 4; ++step) {
                bf16x8 ak = *(const bf16x8*)(Ks + (ts*32 + qc)*128 +
                             ((step*32 + hi*16) ^ ((qc & 7) << 4)));
                st = mfma32(ak, qf[step], st);
            }
            __builtin_amdgcn_s_setprio(0);

            // ---- softmax ----
            float pv[16];
            if (msk) {
#pragma unroll
                for (int rq = 0; rq < 4; ++rq) {
                    const float4 bb = *(const float4*)(mb + t*64 + ts*32 + rq*8 + hi*4);
#pragma unroll
                    for (int e = 0; e < 4; ++e)
                        pv[rq*4 + e] = __builtin_amdgcn_exp2f(st[rq*4 + e] + (&bb.x)[e]);
                }
            } else {
#pragma unroll
                for (int r = 0; r < 16; ++r) pv[r] = __builtin_amdgcn_exp2f(st[r]);
            }
#pragma unroll
            for (int r = 0; r < 16; ++r) lacc += pv[r];

            // ---- P->A-frags (cvt_pk + permlane32_swap) + PV ----
#pragma unroll
            for (int half = 0; half < 2; ++half) {
                unsigned w0 = cvt_pk_bf16(pv[half*8 + 0], pv[half*8 + 1]);
                unsigned w1 = cvt_pk_bf16(pv[half*8 + 2], pv[half*8 + 3]);
                unsigned w2 = cvt_pk_bf16(pv[half*8 + 4], pv[half*8 + 5]);
                unsigned w3 = cvt_pk_bf16(pv[half*8 + 6], pv[half*8 + 7]);
                perm32swap(w0, w2);
                perm32swap(w1, w3);
                uint4v fw; fw[0] = w0; fw[1] = w1; fw[2] = w2; fw[3] = w3;
                const bf16x8 pa = __builtin_bit_cast(bf16x8, fw);
                const int scol = (ts*64 + half*32 + hi*16) ^ ((qc & 7) << 4);
                bf16x8 v0 = *(const bf16x8*)(Vs + qc*128        + scol);
                bf16x8 v1 = *(const bf16x8*)(Vs + (32 + qc)*128 + scol);
                __builtin_amdgcn_s_setprio(1);
                o0 = mfma32(pa, v0, o0);
                o1 = mfma32(pa, v1, o1);
                __builtin_amdgcn_s_setprio(0);
            }
        }

        if (t < 15) {
            char* nxt = smem + ((t + 1) & 1) * 16384;
            *(uint4*)(nxt + woff)               = nK0;
            *(uint4*)(nxt + 4096 + woff)        = nK1;
            *(uint4*)(nxt + 8192 + woff)        = nV0;
            *(uint4*)(nxt + 8192 + 4096 + woff) = nV1;
        }
        __syncthreads();
    }

    // ---- epilogue ----
    {
        unsigned la = __builtin_bit_cast(unsigned, lacc);
        unsigned lb = la;
        perm32swap(la, lb);
        const float ltot = __builtin_bit_cast(float, la) + __builtin_bit_cast(float, lb);
        const float linv = 1.f / ltot;
        if (hi == 0) lbuf[w*32 + qc] = linv;
    }
    __syncthreads();
    float4 li[4];
#pragma unroll
    for (int rq = 0; rq < 4; ++rq)
        li[rq] = *(const float4*)(lbuf + w*32 + rq*8 + hi*4);

#pragma unroll
    for (int dt = 0; dt < 2; ++dt) {
        const f32x16& oo = dt ? o1 : o0;
#pragma unroll
        for (int r = 0; r < 16; ++r) {
            const int qrow = (r & 3) + 8*(r >> 2) + 4*hi;
            const float val = oo[r] * (&li[r >> 2].x)[r & 3];
            Octx[(size_t)(b*T_ + q0 + qrow)*H_ + h*64 + dt*32 + qc] = f2bf(val);
        }
    }
}

// ---------------- residual + LayerNorm ----------------
template<int OUTMODE>   // 0: bf16 out, 1: f32 out
__global__ __launch_bounds__(256)
void ln_kernel(const unsigned short* __restrict__ resid,
               const unsigned short* __restrict__ proj,
               const float* __restrict__ gam,
               const float* __restrict__ bet,
               unsigned short* __restrict__ obf,
               float* __restrict__ of32)
{
    __shared__ float red[8];
    const int tid = threadIdx.x;
    const int lane = tid & 63, w = tid >> 6;
    const int i = tid * 4;
    const size_t base = (size_t)blockIdx.x * 1024 + i;
    uint2 rv = *(const uint2*)(resid + base);
    uint2 pv = *(const uint2*)(proj + base);
    float x[4];
    x[0] = bf2f(rv.x & 0xffffu) + bf2f(pv.x & 0xffffu);
    x[1] = bf2f(rv.x >> 16)     + bf2f(pv.x >> 16);
    x[2] = bf2f(rv.y & 0xffffu) + bf2f(pv.y & 0xffffu);
    x[3] = bf2f(rv.y >> 16)     + bf2f(pv.y >> 16);
    float s = x[0] + x[1] + x[2] + x[3];
    float q = x[0]*x[0] + x[1]*x[1] + x[2]*x[2] + x[3]*x[3];
#pragma unroll
    for (int off = 1; off < 64; off <<= 1) {
        s += __shfl_xor(s, off);
        q += __shfl_xor(q, off);
    }
    if (lane == 0) { red[w*2] = s; red[w*2 + 1] = q; }
    __syncthreads();
    s = red[0] + red[2] + red[4] + red[6];
    q = red[1] + red[3] + red[5] + red[7];
    const float mu   = s * (1.f/1024.f);
    const float var  = q * (1.f/1024.f) - mu*mu;
    const float rstd = rsqrtf(var + 1e-12f);
    const float4 gv = *(const float4*)(gam + i);
    const float4 bv = *(const float4*)(bet + i);
    float y[4];
#pragma unroll
    for (int j = 0; j < 4; j++)
        y[j] = (x[j] - mu) * rstd * (&gv.x)[j] + (&bv.x)[j];
    if (OUTMODE == 0) {
        uint2 oo;
        oo.x = (unsigned)f2bf(y[0]) | ((unsigned)f2bf(y[1]) << 16);
        oo.y = (unsigned)f2bf(y[2]) | ((unsigned)f2bf(y[3]) << 16);
        *(uint2*)(obf + base) = oo;
    } else {
        float4 oo; oo.x = y[0]; oo.y = y[1]; oo.z = y[2]; oo.w = y[3];
        *(float4*)(of32 + base) = oo;
    }
}

extern "C" void kernel_launch(void* const* d_in, const int* in_sizes, int n_in,
                              void* d_out, int out_size, void* d_ws, size_t ws_size,
                              hipStream_t stream)
{
    const float* enc   = (const float*)d_in[0];
    const float* dec   = (const float*)d_in[1];
    const float* smask = (const float*)d_in[2];
    const float* tmask = (const float*)d_in[3];
    const float* Wq = (const float*)d_in[4];
    const float* bq = (const float*)d_in[5];
    const float* Wk = (const float*)d_in[6];
    const float* bk = (const float*)d_in[7];
    const float* Wv = (const float*)d_in[8];
    const float* bv = (const float*)d_in[9];
    const float* Wd = (const float*)d_in[10];
    const float* bd = (const float*)d_in[11];
    const float* lng = (const float*)d_in[12];
    const float* lnb = (const float*)d_in[13];
    float* out = (float*)d_out;

    char* ws = (char*)d_ws;
    const size_t MB = 1024ull * 1024ull;
    unsigned short* dec_bf = (unsigned short*)(ws + 0*MB);
    unsigned short* enc_bf = (unsigned short*)(ws + 8*MB);
    unsigned short* Wq_bf  = (unsigned short*)(ws + 16*MB);
    unsigned short* Wk_bf  = (unsigned short*)(ws + 18*MB);
    unsigned short* Wv_bf  = (unsigned short*)(ws + 20*MB);
    unsigned short* Wd_bf  = (unsigned short*)(ws + 22*MB);
    unsigned short* q1  = (unsigned short*)(ws + 24*MB);
    unsigned short* k1  = (unsigned short*)(ws + 32*MB);
    unsigned short* v1  = (unsigned short*)(ws + 40*MB);
    unsigned short* ek  = (unsigned short*)(ws + 48*MB);
    unsigned short* ev  = (unsigned short*)(ws + 56*MB);
    unsigned short* vt1 = (unsigned short*)(ws + 64*MB);
    unsigned short* ctx      = dec_bf;
    unsigned short* proj     = enc_bf;
    unsigned short* self_out = k1;
    unsigned short* evt      = v1;

    CvtArgs ca;
    ca.src[0] = dec; ca.dst[0] = dec_bf; ca.scale[0] = 1.f;      ca.n4[0] = 1048576;
    ca.src[1] = enc; ca.dst[1] = enc_bf; ca.scale[1] = 1.f;      ca.n4[1] = 1048576;
    ca.src[2] = Wq;  ca.dst[2] = Wq_bf;  ca.scale[2] = 1.f;      ca.n4[2] = 262144;
    ca.src[3] = Wk;  ca.dst[3] = Wk_bf;  ca.scale[3] = SCALE_K;  ca.n4[3] = 262144;
    ca.src[4] = Wv;  ca.dst[4] = Wv_bf;  ca.scale[4] = 1.f;      ca.n4[4] = 262144;
    ca.src[5] = Wd;  ca.dst[5] = Wd_bf;  ca.scale[5] = 1.f;      ca.n4[5] = 262144;
    cvt_multi<<<dim3(4096, 6), 256, 0, stream>>>(ca);

    // merged projections: {dec x Wq,Wk,Wv ; enc x Wk,Wv}, grid y -> set (8 n-tiles each)
    GemmJob j1;
    j1.A[0] = dec_bf; j1.W[0] = Wq_bf; j1.bias[0] = bq; j1.bs[0] = 1.f;     j1.O[0] = q1;
    j1.A[1] = dec_bf; j1.W[1] = Wk_bf; j1.bias[1] = bk; j1.bs[1] = SCALE_K; j1.O[1] = k1;
    j1.A[2] = dec_bf; j1.W[2] = Wv_bf; j1.bias[2] = bv; j1.bs[2] = 1.f;     j1.O[2] = v1;
    j1.A[3] = enc_bf; j1.W[3] = Wk_bf; j1.bias[3] = bk; j1.bs[3] = SCALE_K; j1.O[3] = ek;
    j1.A[4] = enc_bf; j1.W[4] = Wv_bf; j1.bias[4] = bv; j1.bs[4] = 1.f;     j1.O[4] = ev;
    gemm_bf16<<<dim3(32, 40), 256, 0, stream>>>(j1);

    transpose_v<<<dim3(16, 64), 256, 0, stream>>>(v1, vt1);
    transpose_v<<<dim3(16, 64), 256, 0, stream>>>(ev, evt);

    GemmJob jd;
    for (int i = 0; i < 5; i++) {
        jd.A[i] = ctx; jd.W[i] = Wd_bf; jd.bias[i] = bd; jd.bs[i] = 1.f; jd.O[i] = proj;
    }

    // self-attention
    attn_fused2<<<dim3(8, 64), 256, 0, stream>>>(q1, k1, vt1, tmask, ctx);
    gemm_bf16<<<dim3(32, 8), 256, 0, stream>>>(jd);
    ln_kernel<0><<<4096, 256, 0, stream>>>(q1, proj, lng, lnb, self_out, nullptr);

    // cross-attention (query = self_out directly)
    attn_fused2<<<dim3(8, 64), 256, 0, stream>>>(self_out, ek, evt, smask, ctx);
    gemm_bf16<<<dim3(32, 8), 256, 0, stream>>>(jd);
    ln_kernel<1><<<4096, 256, 0, stream>>>(self_out, proj, lng, lnb, nullptr, out);
}